// Round 3
// baseline (390.166 us; speedup 1.0000x reference)
//
#include <hip/hip_runtime.h>

#define N_NODES 100000
#define K_EIG   256
#define C_CH    128
#define BN      320              // rows per split-K chunk
#define NITER   5                // BN/64
#define NCHUNK  313              // ceil(N_NODES / BN); 313*320 = 100160
#define PART_TILE (128*64)       // floats per partial tile (4*313 tiles * 32KB = 41 MB <= d_out 51.2MB)
#define G2_BLOCKS 782            // ceil(N_NODES / 128)

typedef __attribute__((ext_vector_type(8))) short         short8;
typedef __attribute__((ext_vector_type(4))) float         float4v;
typedef __attribute__((ext_vector_type(2))) unsigned int  uint2v;

// fp32 -> bf16 bits with round-to-nearest-even
__device__ __forceinline__ unsigned int bf16_bits(float f) {
  union { float f; unsigned int u; } v; v.f = f;
  unsigned int r = v.u + 0x7fffu + ((v.u >> 16) & 1u);
  return r >> 16;
}
__device__ __forceinline__ unsigned int pack2(float a, float b) {
  return bf16_bits(a) | (bf16_bits(b) << 16);
}

// XOR-swizzled dword index into a k-major LDS tile: row-stride 32 dw (64 bf16).
__device__ __forceinline__ int swz(int row, int nd) {
  return row * 32 + (nd ^ (((row ^ (row >> 3)) & 7) << 2));
}

// ---------------------------------------------------------------------------
// GEMM1: split-K MFMA. Output 256x128 split into 4 tiles of 128k x 64c
// (blockIdx.y = kt*2+ctile), 313 chunks of 320 rows -> 1252 blocks at 6
// blocks/CU capacity (LDS 24KB, launch_bounds(256,6)) -> ~4.9 resident.
// Next-iter global loads are issued BEFORE the first barrier so their latency
// is covered by barrier-wait + MFMA + barrier, and 6 resident blocks per CU
// cover the remainder (kernel is HBM-latency-bound, not LDS/MFMA-bound:
// round-2 counters showed MFMA 3% / VALU 14% / LDS ~8% / HBM 31%).
// ---------------------------------------------------------------------------
__global__ __launch_bounds__(256, 6) void gemm1_kernel(
    const float* __restrict__ x, const float* __restrict__ evecs,
    float* __restrict__ partial) {
  __shared__ __align__(16) unsigned int ev_t[128 * 32];  // [k][n] bf16, swizzled
  __shared__ __align__(16) unsigned int x_t [64 * 32];   // [c][n] bf16, swizzled

  const int tid   = threadIdx.x;
  const int chunk = blockIdx.x;            // 0..NCHUNK-1
  const int tp    = blockIdx.y;            // 0..3 : kt*2 + ctile
  const int kt    = tp >> 1;
  const int ctile = tp & 1;
  const int w  = tid >> 6;                 // wave 0..3 -> k rows [w*32, w*32+32)
  const int l  = tid & 63;
  const int q  = l >> 4;
  const int lc = l & 15;

  // staging mapping: thread owns 4 consecutive n-rows (r4) x 8 ev-k / 4 x-c (k8)
  const int r4 = tid >> 4;                 // 0..15
  const int k8 = tid & 15;                 // 0..15

  float4v acc[2][4];
#pragma unroll
  for (int a = 0; a < 2; a++)
#pragma unroll
    for (int b = 0; b < 4; b++) acc[a][b] = (float4v)0.0f;

  float4v evr[4][2], xr[4];

  auto load_tile = [&](int it) {
    const int nb = chunk * BN + it * 64 + r4 * 4;
#pragma unroll
    for (int r = 0; r < 4; r++) {
      const int n = nb + r;
      const bool ok = (n < N_NODES);
      const float* evp = evecs + (size_t)n * K_EIG + kt * 128 + k8 * 8;
      const float* xp  = x     + (size_t)n * C_CH  + ctile * 64 + k8 * 4;
      evr[r][0] = ok ? *(const float4v*)(evp)     : (float4v)0.0f;
      evr[r][1] = ok ? *(const float4v*)(evp + 4) : (float4v)0.0f;
      xr[r]     = ok ? *(const float4v*)(xp)      : (float4v)0.0f;
    }
  };

  load_tile(0);

  for (int ic = 0; ic < NITER; ic++) {
    // stage current registers into LDS, transposed to k-major (b64 writes)
#pragma unroll
    for (int j = 0; j < 8; j++) {
      const int k = k8 * 8 + j;
      const int d = swz(k, r4 * 2);
      uint2v v;
      v.x = pack2(evr[0][j >> 2][j & 3], evr[1][j >> 2][j & 3]);
      v.y = pack2(evr[2][j >> 2][j & 3], evr[3][j >> 2][j & 3]);
      *(uint2v*)&ev_t[d] = v;
    }
#pragma unroll
    for (int j = 0; j < 4; j++) {
      const int c = k8 * 4 + j;
      const int d = swz(c, r4 * 2);
      uint2v v;
      v.x = pack2(xr[0][j], xr[1][j]);
      v.y = pack2(xr[2][j], xr[3][j]);
      *(uint2v*)&x_t[d] = v;
    }

    // issue next iteration's global loads BEFORE the barrier: latency is
    // covered by barrier-wait + MFMA phase + second barrier
    if (ic + 1 < NITER) load_tile(ic + 1);

    __syncthreads();

#pragma unroll
    for (int ks = 0; ks < 2; ks++) {
      const int nd0 = ks * 16 + q * 4;     // dword offset of the 8-n slice
      short8 afrag[2];
#pragma unroll
      for (int mt = 0; mt < 2; mt++) {
        const int m = w * 32 + mt * 16 + lc;
        afrag[mt] = *(const short8*)&ev_t[swz(m, nd0)];
      }
#pragma unroll
      for (int ct = 0; ct < 4; ct++) {
        const int c = ct * 16 + lc;
        const short8 b = *(const short8*)&x_t[swz(c, nd0)];
        acc[0][ct] = __builtin_amdgcn_mfma_f32_16x16x32_bf16(afrag[0], b, acc[0][ct], 0, 0, 0);
        acc[1][ct] = __builtin_amdgcn_mfma_f32_16x16x32_bf16(afrag[1], b, acc[1][ct], 0, 0, 0);
      }
    }
    __syncthreads();
  }

  // C/D layout: col = lane&15, row = (lane>>4)*4 + reg
  float* pb = partial + (size_t)(tp * NCHUNK + chunk) * PART_TILE;
#pragma unroll
  for (int mt = 0; mt < 2; mt++)
#pragma unroll
    for (int ct = 0; ct < 4; ct++)
#pragma unroll
      for (int r = 0; r < 4; r++) {
        const int m = w * 32 + mt * 16 + q * 4 + r;
        const int c = ct * 16 + lc;
        pb[m * 64 + c] = acc[mt][ct][r];
      }
}

// ---------------------------------------------------------------------------
// Reduce partials, apply exp(-lambda*t), emit bf16 s pre-shuffled into MFMA
// B-fragment order: idx = (((k/32)*8 + c/16)*64 + ((k%32)/8)*16 + (c%16))*8 + k%8
// 2048 blocks x 256 threads: 16 outputs x 16 ch-slices per block (was 512
// blocks = 2/CU, latency-bound on the 32KB-strided gather). 4 independent
// accumulators keep 4+ loads in flight per lane; ~32 waves/CU.
// ---------------------------------------------------------------------------
__global__ __launch_bounds__(256) void reduce_kernel(
    const float* __restrict__ partial, const float* __restrict__ evals,
    const float* __restrict__ dt, unsigned short* __restrict__ s_frag) {
  __shared__ float red[256];
  const int t  = threadIdx.x;
  const int o  = blockIdx.x * 16 + (t & 15);   // output index 0..32767
  const int g  = t >> 4;                       // ch-group 0..15
  const int tp = o >> 13;                      // 0..3
  const int e  = o & 8191;                     // elem within tile
  const float* base = partial + (size_t)tp * NCHUNK * PART_TILE + e;
  float a0 = 0.f, a1 = 0.f, a2 = 0.f, a3 = 0.f;
  int ch = g;
  for (; ch + 48 < NCHUNK; ch += 64) {
    a0 += base[(size_t)(ch     ) * PART_TILE];
    a1 += base[(size_t)(ch + 16) * PART_TILE];
    a2 += base[(size_t)(ch + 32) * PART_TILE];
    a3 += base[(size_t)(ch + 48) * PART_TILE];
  }
  for (; ch < NCHUNK; ch += 16) a0 += base[(size_t)ch * PART_TILE];
  red[t] = (a0 + a1) + (a2 + a3);
  __syncthreads();
  if (t < 16) {
    float tot = 0.f;
#pragma unroll
    for (int g2 = 0; g2 < 16; g2++) tot += red[g2 * 16 + t];
    const int oo = blockIdx.x * 16 + t;
    const int tp2 = oo >> 13;
    const int e2  = oo & 8191;
    const int k = (tp2 >> 1) * 128 + (e2 >> 6);
    const int c = (tp2 & 1) * 64 + (e2 & 63);
    const float tv   = fmaxf(dt[0], 1e-8f);
    const float coef = expf(-evals[k] * tv);
    const float v = tot * coef;
    const int idx = ((((k >> 5) * 8 + (c >> 4)) * 64) + ((k & 31) >> 3) * 16 + (c & 15)) * 8 + (k & 7);
    s_frag[idx] = (unsigned short)bf16_bits(v);
  }
}

// ---------------------------------------------------------------------------
// GEMM2: out[n][c] = sum_k evecs[n][k] * s[k][c]
// No LDS: B-fragments stream from the fragment-ordered 64KB s buffer.
// Per ks: ALL 8 b-frag loads are hoisted into registers ahead of the MFMA
// cluster (8 L2 loads in flight instead of one ~200cy stall per ct), then
// next-ks A loads, then the a-build VALU covers the load latency.
// ---------------------------------------------------------------------------
__global__ __launch_bounds__(256, 3) void gemm2_kernel(
    const float* __restrict__ evecs, const unsigned short* __restrict__ s_frag,
    float* __restrict__ out) {
  const int tid = threadIdx.x;
  const int w  = tid >> 6, l = tid & 63, q = l >> 4, lc = l & 15;
  const int rowbase = blockIdx.x * 128 + w * 32;

  int n0 = rowbase + lc;        n0 = (n0 < N_NODES) ? n0 : (N_NODES - 1);
  int n1 = rowbase + 16 + lc;   n1 = (n1 < N_NODES) ? n1 : (N_NODES - 1);
  const float* row0 = evecs + (size_t)n0 * K_EIG + q * 8;
  const float* row1 = evecs + (size_t)n1 * K_EIG + q * 8;

  float4v acc[2][8];
#pragma unroll
  for (int a = 0; a < 2; a++)
#pragma unroll
    for (int b = 0; b < 8; b++) acc[a][b] = (float4v)0.0f;

  float4v c00 = *(const float4v*)(row0);
  float4v c01 = *(const float4v*)(row0 + 4);
  float4v c10 = *(const float4v*)(row1);
  float4v c11 = *(const float4v*)(row1 + 4);

#pragma unroll
  for (int ks = 0; ks < 8; ks++) {
    // hoist: 8 b-frag loads in flight
    short8 bfr[8];
#pragma unroll
    for (int ct = 0; ct < 8; ct++)
      bfr[ct] = *(const short8*)&s_frag[(size_t)((ks * 8 + ct) * 64 + l) * 8];
    // next-ks A loads in flight
    float4v nx00, nx01, nx10, nx11;
    if (ks < 7) {
      nx00 = *(const float4v*)(row0 + (ks + 1) * 32);
      nx01 = *(const float4v*)(row0 + (ks + 1) * 32 + 4);
      nx10 = *(const float4v*)(row1 + (ks + 1) * 32);
      nx11 = *(const float4v*)(row1 + (ks + 1) * 32 + 4);
    }
    // a-build VALU covers the outstanding loads
    short8 a0, a1;
    a0[0] = (short)bf16_bits(c00.x); a0[1] = (short)bf16_bits(c00.y);
    a0[2] = (short)bf16_bits(c00.z); a0[3] = (short)bf16_bits(c00.w);
    a0[4] = (short)bf16_bits(c01.x); a0[5] = (short)bf16_bits(c01.y);
    a0[6] = (short)bf16_bits(c01.z); a0[7] = (short)bf16_bits(c01.w);
    a1[0] = (short)bf16_bits(c10.x); a1[1] = (short)bf16_bits(c10.y);
    a1[2] = (short)bf16_bits(c10.z); a1[3] = (short)bf16_bits(c10.w);
    a1[4] = (short)bf16_bits(c11.x); a1[5] = (short)bf16_bits(c11.y);
    a1[6] = (short)bf16_bits(c11.z); a1[7] = (short)bf16_bits(c11.w);
#pragma unroll
    for (int ct = 0; ct < 8; ct++) {
      acc[0][ct] = __builtin_amdgcn_mfma_f32_16x16x32_bf16(a0, bfr[ct], acc[0][ct], 0, 0, 0);
      acc[1][ct] = __builtin_amdgcn_mfma_f32_16x16x32_bf16(a1, bfr[ct], acc[1][ct], 0, 0, 0);
    }
    c00 = nx00; c01 = nx01; c10 = nx10; c11 = nx11;
  }

#pragma unroll
  for (int rt = 0; rt < 2; rt++)
#pragma unroll
    for (int ct = 0; ct < 8; ct++)
#pragma unroll
      for (int r = 0; r < 4; r++) {
        const int n = rowbase + rt * 16 + q * 4 + r;
        if (n < N_NODES) out[(size_t)n * C_CH + ct * 16 + lc] = acc[rt][ct][r];
      }
}

// ---------------------------------------------------------------------------
extern "C" void kernel_launch(void* const* d_in, const int* in_sizes, int n_in,
                              void* d_out, int out_size, void* d_ws, size_t ws_size,
                              hipStream_t stream) {
  const float* x     = (const float*)d_in[0];   // [N, C]
  const float* evals = (const float*)d_in[1];   // [K]
  const float* evecs = (const float*)d_in[2];   // [N, K]
  const float* dt    = (const float*)d_in[3];   // [1]
  float* out = (float*)d_out;                   // [N, C] fp32

  // d_out doubles as split-K partial scratch: 4*313 tiles * 32KB = 41 MB <= 51.2 MB.
  float* partial = out;
  unsigned short* s_frag = (unsigned short*)d_ws;  // 64 KB bf16, fragment-ordered

  dim3 g1(NCHUNK, 4);
  gemm1_kernel<<<g1, 256, 0, stream>>>(x, evecs, partial);
  reduce_kernel<<<2048, 256, 0, stream>>>(partial, evals, dt, s_frag);
  gemm2_kernel<<<G2_BLOCKS, 256, 0, stream>>>(evecs, s_frag, out);
}

// Round 4
// 243.871 us; speedup vs baseline: 1.5999x; 1.5999x over previous
//
#include <hip/hip_runtime.h>

#define N_NODES 100000
#define K_EIG   256
#define C_CH    128
#define BN      384              // rows per split-K chunk
#define NITER   6                // BN/64
#define NCHUNK  261              // ceil(N_NODES / BN); 261*384 = 100224
#define PART_TILE (128*64)       // floats per partial tile (4*261 tiles * 32KB = 33.4 MB <= d_out)
#define G2_BLOCKS 782            // ceil(N_NODES / 128)

typedef __attribute__((ext_vector_type(8))) short         short8;
typedef __attribute__((ext_vector_type(4))) float         float4v;
typedef __attribute__((ext_vector_type(2))) unsigned int  uint2v;

// fp32 -> bf16 bits with round-to-nearest-even
__device__ __forceinline__ unsigned int bf16_bits(float f) {
  union { float f; unsigned int u; } v; v.f = f;
  unsigned int r = v.u + 0x7fffu + ((v.u >> 16) & 1u);
  return r >> 16;
}
__device__ __forceinline__ unsigned int pack2(float a, float b) {
  return bf16_bits(a) | (bf16_bits(b) << 16);
}

// XOR-swizzled dword index into a k-major LDS tile: row-stride 32 dw (64 bf16).
__device__ __forceinline__ int swz(int row, int nd) {
  return row * 32 + (nd ^ (((row ^ (row >> 3)) & 7) << 2));
}

// ---------------------------------------------------------------------------
// GEMM1: split-K MFMA, EXACT round-2 configuration (measured 75-78us there).
// launch_bounds(256,4): VGPR cap 128 >> 64 live -- the round-3 regression was
// launch_bounds(256,6) capping VGPR below the 48-reg prefetch pipeline ->
// scratch spills (VGPR 40, WRITE_SIZE 330MB, 202us). Do not raise waves/EU
// without re-checking VGPR_Count==64 and WRITE_SIZE==33MB.
// ---------------------------------------------------------------------------
__global__ __launch_bounds__(256, 4) void gemm1_kernel(
    const float* __restrict__ x, const float* __restrict__ evecs,
    float* __restrict__ partial) {
  __shared__ __align__(16) unsigned int ev_t[128 * 32];  // [k][n] bf16, swizzled
  __shared__ __align__(16) unsigned int x_t [64 * 32];   // [c][n] bf16, swizzled

  const int tid   = threadIdx.x;
  const int chunk = blockIdx.x;            // 0..NCHUNK-1
  const int tp    = blockIdx.y;            // 0..3 : kt*2 + ctile
  const int kt    = tp >> 1;
  const int ctile = tp & 1;
  const int w  = tid >> 6;                 // wave 0..3 -> k rows [w*32, w*32+32)
  const int l  = tid & 63;
  const int q  = l >> 4;
  const int lc = l & 15;

  // staging mapping: thread owns 4 consecutive n-rows (r4) x 8 ev-k / 4 x-c (k8)
  const int r4 = tid >> 4;                 // 0..15
  const int k8 = tid & 15;                 // 0..15

  float4v acc[2][4];
#pragma unroll
  for (int a = 0; a < 2; a++)
#pragma unroll
    for (int b = 0; b < 4; b++) acc[a][b] = (float4v)0.0f;

  float4v evr[4][2], xr[4];

  auto load_tile = [&](int it) {
    const int nb = chunk * BN + it * 64 + r4 * 4;
#pragma unroll
    for (int r = 0; r < 4; r++) {
      const int n = nb + r;
      const bool ok = (n < N_NODES);
      const float* evp = evecs + (size_t)n * K_EIG + kt * 128 + k8 * 8;
      const float* xp  = x     + (size_t)n * C_CH  + ctile * 64 + k8 * 4;
      evr[r][0] = ok ? *(const float4v*)(evp)     : (float4v)0.0f;
      evr[r][1] = ok ? *(const float4v*)(evp + 4) : (float4v)0.0f;
      xr[r]     = ok ? *(const float4v*)(xp)      : (float4v)0.0f;
    }
  };

  load_tile(0);

  for (int ic = 0; ic < NITER; ic++) {
    // stage current registers into LDS, transposed to k-major (b64 writes)
#pragma unroll
    for (int j = 0; j < 8; j++) {
      const int k = k8 * 8 + j;
      const int d = swz(k, r4 * 2);
      uint2v v;
      v.x = pack2(evr[0][j >> 2][j & 3], evr[1][j >> 2][j & 3]);
      v.y = pack2(evr[2][j >> 2][j & 3], evr[3][j >> 2][j & 3]);
      *(uint2v*)&ev_t[d] = v;
    }
#pragma unroll
    for (int j = 0; j < 4; j++) {
      const int c = k8 * 4 + j;
      const int d = swz(c, r4 * 2);
      uint2v v;
      v.x = pack2(xr[0][j], xr[1][j]);
      v.y = pack2(xr[2][j], xr[3][j]);
      *(uint2v*)&x_t[d] = v;
    }
    __syncthreads();

    // issue next iteration's global loads now; they complete during compute
    if (ic + 1 < NITER) load_tile(ic + 1);

#pragma unroll
    for (int ks = 0; ks < 2; ks++) {
      const int nd0 = ks * 16 + q * 4;     // dword offset of the 8-n slice
      short8 afrag[2];
#pragma unroll
      for (int mt = 0; mt < 2; mt++) {
        const int m = w * 32 + mt * 16 + lc;
        afrag[mt] = *(const short8*)&ev_t[swz(m, nd0)];
      }
#pragma unroll
      for (int ct = 0; ct < 4; ct++) {
        const int c = ct * 16 + lc;
        const short8 b = *(const short8*)&x_t[swz(c, nd0)];
        acc[0][ct] = __builtin_amdgcn_mfma_f32_16x16x32_bf16(afrag[0], b, acc[0][ct], 0, 0, 0);
        acc[1][ct] = __builtin_amdgcn_mfma_f32_16x16x32_bf16(afrag[1], b, acc[1][ct], 0, 0, 0);
      }
    }
    __syncthreads();
  }

  // C/D layout: col = lane&15, row = (lane>>4)*4 + reg
  float* pb = partial + (size_t)(tp * NCHUNK + chunk) * PART_TILE;
#pragma unroll
  for (int mt = 0; mt < 2; mt++)
#pragma unroll
    for (int ct = 0; ct < 4; ct++)
#pragma unroll
      for (int r = 0; r < 4; r++) {
        const int m = w * 32 + mt * 16 + q * 4 + r;
        const int c = ct * 16 + lc;
        pb[m * 64 + c] = acc[mt][ct][r];
      }
}

// ---------------------------------------------------------------------------
// Reduce partials, apply exp(-lambda*t), emit bf16 s pre-shuffled into MFMA
// B-fragment order: idx = (((k/32)*8 + c/16)*64 + ((k%32)/8)*16 + (c%16))*8 + k%8
// 1024 blocks (4/CU) x 32 consecutive outputs: each wave access = two full
// 128B line segments; 8 chunk-lanes x 4 independent accumulators -> ~16KB in
// flight per CU (> ~9KB needed for HBM latency x BW). Round-2 version was
// 512 blocks = 2/CU, latency-underfed.
// ---------------------------------------------------------------------------
__global__ __launch_bounds__(256) void reduce_kernel(
    const float* __restrict__ partial, const float* __restrict__ evals,
    const float* __restrict__ dt, unsigned short* __restrict__ s_frag) {
  __shared__ float red[256];
  const int t  = threadIdx.x;
  const int o  = blockIdx.x * 32 + (t & 31);   // output index 0..32767
  const int p  = t >> 5;                       // chunk-lane 0..7
  const int tp = o >> 13;                      // 0..3
  const int e  = o & 8191;                     // elem within tile
  const float* base = partial + (size_t)tp * NCHUNK * PART_TILE + e;
  float a0 = 0.f, a1 = 0.f, a2 = 0.f, a3 = 0.f;
  int ch = p;
  for (; ch + 24 < NCHUNK; ch += 32) {
    a0 += base[(size_t)(ch     ) * PART_TILE];
    a1 += base[(size_t)(ch +  8) * PART_TILE];
    a2 += base[(size_t)(ch + 16) * PART_TILE];
    a3 += base[(size_t)(ch + 24) * PART_TILE];
  }
  for (; ch < NCHUNK; ch += 8) a0 += base[(size_t)ch * PART_TILE];
  red[t] = (a0 + a1) + (a2 + a3);
  __syncthreads();
  if (t < 32) {
    float tot = 0.f;
#pragma unroll
    for (int g = 0; g < 8; g++) tot += red[g * 32 + t];
    const int oo = blockIdx.x * 32 + t;
    const int tp2 = oo >> 13;
    const int e2  = oo & 8191;
    const int k = (tp2 >> 1) * 128 + (e2 >> 6);
    const int c = (tp2 & 1) * 64 + (e2 & 63);
    const float tv   = fmaxf(dt[0], 1e-8f);
    const float coef = expf(-evals[k] * tv);
    const float v = tot * coef;
    const int idx = ((((k >> 5) * 8 + (c >> 4)) * 64) + ((k & 31) >> 3) * 16 + (c & 15)) * 8 + (k & 7);
    s_frag[idx] = (unsigned short)bf16_bits(v);
  }
}

// ---------------------------------------------------------------------------
// GEMM2: out[n][c] = sum_k evecs[n][k] * s[k][c]
// B is LDS-RESIDENT: each block copies the full 64KB fragment-ordered s
// buffer into LDS once (coalesced L2 reads), so the 64 B-fragment reads per
// wave are ds_read_b128 (~12cy) instead of ~250cy L2 loads serialized
// against dependent MFMAs. A-rows keep the ks+1 register prefetch, issued
// before the copy so they fly during it. 64KB LDS -> 2 blocks/CU
// (launch_bounds(256,2): VGPR cap 256, ~140 live, no spill risk).
// ---------------------------------------------------------------------------
__global__ __launch_bounds__(256, 2) void gemm2_kernel(
    const float* __restrict__ evecs, const unsigned short* __restrict__ s_frag,
    float* __restrict__ out) {
  __shared__ __align__(16) unsigned short s_lds[32768];  // 64 KB

  const int tid = threadIdx.x;
  const int w  = tid >> 6, l = tid & 63, q = l >> 4, lc = l & 15;
  const int rowbase = blockIdx.x * 128 + w * 32;

  int n0 = rowbase + lc;        n0 = (n0 < N_NODES) ? n0 : (N_NODES - 1);
  int n1 = rowbase + 16 + lc;   n1 = (n1 < N_NODES) ? n1 : (N_NODES - 1);
  const float* row0 = evecs + (size_t)n0 * K_EIG + q * 8;
  const float* row1 = evecs + (size_t)n1 * K_EIG + q * 8;

  // issue first A loads before the copy: they complete during it
  float4v c00 = *(const float4v*)(row0);
  float4v c01 = *(const float4v*)(row0 + 4);
  float4v c10 = *(const float4v*)(row1);
  float4v c11 = *(const float4v*)(row1 + 4);

  // copy s_frag -> LDS: 16 iters x 256 threads x 16B = 64KB, coalesced
#pragma unroll
  for (int i = 0; i < 16; i++) {
    const int off = (i * 256 + tid) * 8;   // in shorts
    *(short8*)&s_lds[off] = *(const short8*)&s_frag[off];
  }

  float4v acc[2][8];
#pragma unroll
  for (int a = 0; a < 2; a++)
#pragma unroll
    for (int b = 0; b < 8; b++) acc[a][b] = (float4v)0.0f;

  __syncthreads();

#pragma unroll
  for (int ks = 0; ks < 8; ks++) {
    // next-ks A loads in flight during this ks's compute
    float4v nx00, nx01, nx10, nx11;
    if (ks < 7) {
      nx00 = *(const float4v*)(row0 + (ks + 1) * 32);
      nx01 = *(const float4v*)(row0 + (ks + 1) * 32 + 4);
      nx10 = *(const float4v*)(row1 + (ks + 1) * 32);
      nx11 = *(const float4v*)(row1 + (ks + 1) * 32 + 4);
    }
    // B fragments from LDS (conflict-free: lane-contiguous 16B)
    short8 bfr[8];
#pragma unroll
    for (int ct = 0; ct < 8; ct++)
      bfr[ct] = *(const short8*)&s_lds[(size_t)((ks * 8 + ct) * 64 + l) * 8];
    short8 a0, a1;
    a0[0] = (short)bf16_bits(c00.x); a0[1] = (short)bf16_bits(c00.y);
    a0[2] = (short)bf16_bits(c00.z); a0[3] = (short)bf16_bits(c00.w);
    a0[4] = (short)bf16_bits(c01.x); a0[5] = (short)bf16_bits(c01.y);
    a0[6] = (short)bf16_bits(c01.z); a0[7] = (short)bf16_bits(c01.w);
    a1[0] = (short)bf16_bits(c10.x); a1[1] = (short)bf16_bits(c10.y);
    a1[2] = (short)bf16_bits(c10.z); a1[3] = (short)bf16_bits(c10.w);
    a1[4] = (short)bf16_bits(c11.x); a1[5] = (short)bf16_bits(c11.y);
    a1[6] = (short)bf16_bits(c11.z); a1[7] = (short)bf16_bits(c11.w);
#pragma unroll
    for (int ct = 0; ct < 8; ct++) {
      acc[0][ct] = __builtin_amdgcn_mfma_f32_16x16x32_bf16(a0, bfr[ct], acc[0][ct], 0, 0, 0);
      acc[1][ct] = __builtin_amdgcn_mfma_f32_16x16x32_bf16(a1, bfr[ct], acc[1][ct], 0, 0, 0);
    }
    c00 = nx00; c01 = nx01; c10 = nx10; c11 = nx11;
  }

#pragma unroll
  for (int rt = 0; rt < 2; rt++)
#pragma unroll
    for (int ct = 0; ct < 8; ct++)
#pragma unroll
      for (int r = 0; r < 4; r++) {
        const int n = rowbase + rt * 16 + q * 4 + r;
        if (n < N_NODES) out[(size_t)n * C_CH + ct * 16 + lc] = acc[rt][ct][r];
      }
}

// ---------------------------------------------------------------------------
extern "C" void kernel_launch(void* const* d_in, const int* in_sizes, int n_in,
                              void* d_out, int out_size, void* d_ws, size_t ws_size,
                              hipStream_t stream) {
  const float* x     = (const float*)d_in[0];   // [N, C]
  const float* evals = (const float*)d_in[1];   // [K]
  const float* evecs = (const float*)d_in[2];   // [N, K]
  const float* dt    = (const float*)d_in[3];   // [1]
  float* out = (float*)d_out;                   // [N, C] fp32

  // d_out doubles as split-K partial scratch: 4*261 tiles * 32KB = 33.4 MB <= 51.2 MB.
  float* partial = out;
  unsigned short* s_frag = (unsigned short*)d_ws;  // 64 KB bf16, fragment-ordered

  dim3 g1(NCHUNK, 4);
  gemm1_kernel<<<g1, 256, 0, stream>>>(x, evecs, partial);
  reduce_kernel<<<1024, 256, 0, stream>>>(partial, evals, dt, s_frag);
  gemm2_kernel<<<G2_BLOCKS, 256, 0, stream>>>(evecs, s_frag, out);
}